// Round 11
// baseline (344.362 us; speedup 1.0000x reference)
//
#include <hip/hip_runtime.h>

// upfirdn2d: UP=1, DOWN=2, PAD=5, 12x12 separable sym6 kernel.
// v9: ONE WAVE PER BLOCK (64 thr), 8x64 output tile, wave-private 4.6 KB LDS,
//     ZERO inter-wave synchronization. Theory: r7/r9/r10 all pinned at ~70us
//     because barrier-coupled V(load)/H(LDS) phases align CU-wide and the
//     memory pipe idles during H-windows. Independent waves drift and
//     interleave V/H across the CU. __launch_bounds__(64,6) -> <=85 VGPR,
//     ~24 waves/CU (same count as r7; coupling is the only variable removed).

#define H_IN  256
#define W_IN  256
#define H_OUT 128
#define W_OUT 128
#define KTAP  12
#define VSTR  144   // vs row stride in words (576 B, 8/16B aligned accesses ok)

typedef float f32x4 __attribute__((ext_vector_type(4)));

__global__ __launch_bounds__(64, 6)
void upfirdn2d_sym6(const float* __restrict__ x,
                    const float* __restrict__ k2d,
                    float* __restrict__ out) {
    __shared__ float vs[8 * VSTR];     // 4.6 KB vertical intermediate
    __shared__ float ks[KTAP * KTAP];
    __shared__ float wsh[KTAP];

    const int tid = threadIdx.x;

    // --- derive flipped separable taps from the 12x12 outer-product kernel
    for (int i = tid; i < KTAP * KTAP; i += 64) ks[i] = k2d[i];
    __syncthreads();   // 1-wave block: just an s_barrier, effectively free
    if (tid < KTAP) {
        float tot = 0.f;
        #pragma unroll
        for (int i = 0; i < KTAP * KTAP; ++i) tot += ks[i];
        float rs = 0.f;
        #pragma unroll
        for (int q = 0; q < KTAP; ++q) rs += ks[(KTAP - 1 - tid) * KTAP + q];
        wsh[tid] = rs * rsqrtf(tot);   // w[p] = h[11-p]
    }
    __syncthreads();
    float w[KTAP];
    #pragma unroll
    for (int p = 0; p < KTAP; ++p) w[p] = wsh[p];

    const int img = blockIdx.y;            // 0..1023
    const int tr  = blockIdx.x >> 1;       // 0..15 (8 out-rows each)
    const int tj  = blockIdx.x & 1;        // 0..1  (64 out-cols each)
    const float* xim = x + (size_t)img * (H_IN * W_IN);
    float* oim = out + (size_t)img * (H_OUT * W_OUT);

    const int gc0 = 128 * tj - 8;          // input col of frame word 0 (16B-aligned)
    const int gr0 = 16 * tr - 5;           // first input row of the 26-row window

    // ---- vertical pass: lanes 0..35, lane owns 4 frame cols x 8 out rows
    if (tid < 36) {
        const int col = gc0 + 4 * tid;
        const bool colok = (unsigned)col < (unsigned)W_IN;
        float4 acc[8];
        #pragma unroll
        for (int k = 0; k < 8; ++k) acc[k] = make_float4(0.f, 0.f, 0.f, 0.f);

        const float* rp = xim + (size_t)gr0 * W_IN + col;
        #pragma unroll
        for (int rr = 0; rr < 26; ++rr) {
            const int gr = gr0 + rr;       // wave-uniform row bound check
            float4 v = make_float4(0.f, 0.f, 0.f, 0.f);
            if (colok && (unsigned)gr < (unsigned)H_IN)
                v = *reinterpret_cast<const float4*>(rp);
            rp += W_IN;
            #pragma unroll
            for (int ri = 0; ri < 8; ++ri) {
                const int p = rr - 2 * ri;  // compile-time tap index
                if (p >= 0 && p < KTAP) {
                    acc[ri].x = fmaf(w[p], v.x, acc[ri].x);
                    acc[ri].y = fmaf(w[p], v.y, acc[ri].y);
                    acc[ri].z = fmaf(w[p], v.z, acc[ri].z);
                    acc[ri].w = fmaf(w[p], v.w, acc[ri].w);
                }
            }
        }
        #pragma unroll
        for (int ri = 0; ri < 8; ++ri)
            *reinterpret_cast<float4*>(&vs[ri * VSTR + 4 * tid]) = acc[ri];
    }
    // No barrier: same wave wrote vs; DS ops execute in order within a wave
    // and the compiler orders accesses to the same __shared__ array.
    __syncthreads();   // single-wave s_barrier, kept for safety (near-free)

    // ---- horizontal pass: lane j = out col; out col j needs f[2j+3 .. 2j+14]
    // read words 2j+2 .. 2j+15 as 7x float2 (byte 8j+8: 8B-aligned), use [1..12]
    #pragma unroll
    for (int i = 0; i < 8; ++i) {
        const float* base = &vs[i * VSTR + 2 * tid + 2];
        float f[14];
        #pragma unroll
        for (int m = 0; m < 7; ++m) {
            float2 t2 = *reinterpret_cast<const float2*>(base + 2 * m);
            f[2*m]   = t2.x;
            f[2*m+1] = t2.y;
        }
        float a = 0.f;
        #pragma unroll
        for (int q = 0; q < KTAP; ++q)
            a = fmaf(w[q], f[q + 1], a);
        float* dst = oim + (size_t)(8 * tr + i) * W_OUT + 64 * tj + tid;
        __builtin_nontemporal_store(a, dst);
    }
}

extern "C" void kernel_launch(void* const* d_in, const int* in_sizes, int n_in,
                              void* d_out, int out_size, void* d_ws, size_t ws_size,
                              hipStream_t stream) {
    const float* x   = (const float*)d_in[0];
    const float* k2d = (const float*)d_in[1];
    float* out       = (float*)d_out;

    // 16x2 tiles of 8x64 outputs per image, 1024 images
    dim3 grid(32, 1024);
    dim3 block(64);
    upfirdn2d_sym6<<<grid, block, 0, stream>>>(x, k2d, out);
}

// Round 12
// 73.205 us; speedup vs baseline: 4.7041x; 4.7041x over previous
//
#include <hip/hip_runtime.h>

// upfirdn2d: UP=1, DOWN=2, PAD=5, 12x12 separable sym6 kernel.
// v10: r7 structure (32x64 tile, 192 thr, f32 LDS VSTR=148, float4 sliding
//      window V-pass, nt f32x4 stores) with the per-block overhead removed:
//      - cheap tap derivation: 12 lanes compute row sums in registers from
//        3 aligned float4 loads (was: 144-element unrolled LDS sum = ~1100cy)
//      - grid-stride over 4 images per block: prologue amortized 4x, grid =
//        2048 blocks = exactly 8/CU resident (zero ramp rounds)
//      NT stores kept vectorized only (r11 lesson: scalar nt = 8.5x WRITE).

#define H_IN  256
#define W_IN  256
#define H_OUT 128
#define W_OUT 128
#define KTAP  12
#define OTR   32    // output tile rows
#define OTC   64    // output tile cols
#define VSTR  148   // vs row stride (words)
#define NTHR  192
#define NIMG  1024
#define IMG_STRIDE 256   // blockIdx.y range; 4 images per block

typedef float f32x4 __attribute__((ext_vector_type(4)));

__global__ __launch_bounds__(NTHR)
void upfirdn2d_sym6(const float* __restrict__ x,
                    const float* __restrict__ k2d,
                    float* __restrict__ out) {
    __shared__ float vs[OTR * VSTR];   // 32 x 148 x 4B = 18.5 KB
    __shared__ float rsum[KTAP];

    const int tid = threadIdx.x;

    // --- cheap tap derivation: k2d[p][q] = h[p]h[q]; rowsum[p] = h[p]*S,
    //     tot = S^2; w[p] = h[11-p] = rowsum[11-p]/sqrt(tot)
    if (tid < KTAP) {
        const float4* kp = reinterpret_cast<const float4*>(k2d + 12 * tid); // 48B offsets: 16B-aligned
        float4 a = kp[0], b = kp[1], c = kp[2];
        rsum[tid] = ((a.x + a.y) + (a.z + a.w))
                  + ((b.x + b.y) + (b.z + b.w))
                  + ((c.x + c.y) + (c.z + c.w));
    }
    __syncthreads();
    float w[KTAP];
    {
        float tot = 0.f;
        #pragma unroll
        for (int q = 0; q < KTAP; ++q) tot += rsum[q];
        const float r = rsqrtf(tot);
        #pragma unroll
        for (int p = 0; p < KTAP; ++p) w[p] = rsum[KTAP - 1 - p] * r;
    }

    const int ti  = blockIdx.x >> 1;       // row tile 0..3 (32 out rows each)
    const int tj  = blockIdx.x & 1;        // col tile 0..1 (64 out cols each)
    const int gc0 = 128 * tj - 8;          // global col of frame word 0 (4-aligned)
    const bool edge_rows = (ti == 0) || (ti == 3);   // block-uniform

    // --- vertical-pass task decode (loop-invariant)
    const int rg  = tid / 36;
    const int cg  = tid - rg * 36;
    const int col = gc0 + 4 * cg;
    const bool colok = (unsigned)col < (unsigned)W_IN;
    const int i0  = rg * 8;
    const int gr0 = 64 * ti + 16 * rg - 5;

    for (int img = blockIdx.y; img < NIMG; img += IMG_STRIDE) {
        const float* xim = x + (size_t)img * (H_IN * W_IN);
        float* oim = out + (size_t)img * (H_OUT * W_OUT);

        // ---- vertical pass: 144 tasks, 8 out-rows x 4 cols each
        if (tid < 144) {
            float4 acc[8];
            #pragma unroll
            for (int k = 0; k < 8; ++k) acc[k] = make_float4(0.f, 0.f, 0.f, 0.f);

            if (!edge_rows) {
                const float* rp = xim + (size_t)gr0 * W_IN + col;
                #pragma unroll
                for (int rr = 0; rr < 26; ++rr) {
                    float4 v = make_float4(0.f, 0.f, 0.f, 0.f);
                    if (colok) v = *reinterpret_cast<const float4*>(rp);
                    rp += W_IN;
                    #pragma unroll
                    for (int ri = 0; ri < 8; ++ri) {
                        const int p = rr - 2 * ri;      // compile-time tap index
                        if (p >= 0 && p < KTAP) {
                            acc[ri].x = fmaf(w[p], v.x, acc[ri].x);
                            acc[ri].y = fmaf(w[p], v.y, acc[ri].y);
                            acc[ri].z = fmaf(w[p], v.z, acc[ri].z);
                            acc[ri].w = fmaf(w[p], v.w, acc[ri].w);
                        }
                    }
                }
            } else {
                #pragma unroll
                for (int rr = 0; rr < 26; ++rr) {
                    const int gr = gr0 + rr;
                    float4 v = make_float4(0.f, 0.f, 0.f, 0.f);
                    if (colok && (unsigned)gr < (unsigned)H_IN)
                        v = *reinterpret_cast<const float4*>(xim + gr * W_IN + col);
                    #pragma unroll
                    for (int ri = 0; ri < 8; ++ri) {
                        const int p = rr - 2 * ri;
                        if (p >= 0 && p < KTAP) {
                            acc[ri].x = fmaf(w[p], v.x, acc[ri].x);
                            acc[ri].y = fmaf(w[p], v.y, acc[ri].y);
                            acc[ri].z = fmaf(w[p], v.z, acc[ri].z);
                            acc[ri].w = fmaf(w[p], v.w, acc[ri].w);
                        }
                    }
                }
            }
            #pragma unroll
            for (int ri = 0; ri < 8; ++ri)
                *reinterpret_cast<float4*>(&vs[(i0 + ri) * VSTR + 4 * cg]) = acc[ri];
        }
        __syncthreads();

        // ---- horizontal pass: 256 tasks (i 0..31 x g 0..7), 8 outputs each
        for (int t = tid; t < 256; t += NTHR) {
            const int i = t >> 3;
            const int g = t & 7;

            float f[32];
            #pragma unroll
            for (int m = 0; m < 8; ++m) {
                float4 v4 = *reinterpret_cast<const float4*>(&vs[i * VSTR + 16 * g + 4 * m]);
                f[4*m+0] = v4.x; f[4*m+1] = v4.y; f[4*m+2] = v4.z; f[4*m+3] = v4.w;
            }
            float o[8];
            #pragma unroll
            for (int jj = 0; jj < 8; ++jj) {
                float a = 0.f;
                #pragma unroll
                for (int q = 0; q < KTAP; ++q)
                    a = fmaf(w[q], f[2*jj + 3 + q], a);
                o[jj] = a;
            }
            const int orow = ti * OTR + i;
            const int ocol = tj * OTC + 8 * g;
            f32x4 o0 = { o[0], o[1], o[2], o[3] };
            f32x4 o1 = { o[4], o[5], o[6], o[7] };
            float* dst = oim + (size_t)orow * W_OUT + ocol;
            __builtin_nontemporal_store(o0, reinterpret_cast<f32x4*>(dst));
            __builtin_nontemporal_store(o1, reinterpret_cast<f32x4*>(dst + 4));
        }
        __syncthreads();   // protect vs before next image's V-pass
    }
}

extern "C" void kernel_launch(void* const* d_in, const int* in_sizes, int n_in,
                              void* d_out, int out_size, void* d_ws, size_t ws_size,
                              hipStream_t stream) {
    const float* x   = (const float*)d_in[0];
    const float* k2d = (const float*)d_in[1];
    float* out       = (float*)d_out;

    // 4x2 tiles of 32x64 per image; 256 image-slots x 4 images grid-stride
    dim3 grid(8, IMG_STRIDE);
    dim3 block(NTHR);
    upfirdn2d_sym6<<<grid, block, 0, stream>>>(x, k2d, out);
}

// Round 13
// 62.904 us; speedup vs baseline: 5.4744x; 1.1637x over previous
//
#include <hip/hip_runtime.h>

// upfirdn2d: UP=1, DOWN=2, PAD=5, 12x12 separable sym6 kernel.
// v11: FULL-WIDTH tiles (32x128 out) -> each block reads 42 whole input rows
//      contiguously (1 KB full-wave loads, linear walk; copy-like DRAM burst
//      pattern, zero column halo). XCD-chunked bijective swizzle: ti-adjacent
//      tiles (10-row halo overlap) run consecutively on the SAME XCD L2.
//      16-row V tasks (136 <= 256 thr), f32 LDS 32x276 (35.3 KB),
//      nt f32x4 stores.

#define H_IN  256
#define W_IN  256
#define H_OUT 128
#define W_OUT 128
#define KTAP  12
#define VSTR  276    // LDS row stride in words (mult of 4; %32==20 spreads banks)
#define FG    68     // frame float4-groups per row (words 0..271 <-> cols -8..263)
#define NTHR  256

typedef float f32x4 __attribute__((ext_vector_type(4)));

__global__ __launch_bounds__(NTHR)
void upfirdn2d_sym6(const float* __restrict__ x,
                    const float* __restrict__ k2d,
                    float* __restrict__ out) {
    __shared__ float vs[32 * VSTR];   // 35.3 KB
    __shared__ float rsum[KTAP];

    const int tid = threadIdx.x;

    // --- cheap tap derivation: k2d[p][q]=h[p]h[q]; w[p]=h[11-p]=rowsum[11-p]/sqrt(tot)
    if (tid < KTAP) {
        const float4* kp = reinterpret_cast<const float4*>(k2d + 12 * tid);
        float4 a = kp[0], b = kp[1], c = kp[2];
        rsum[tid] = ((a.x + a.y) + (a.z + a.w))
                  + ((b.x + b.y) + (b.z + b.w))
                  + ((c.x + c.y) + (c.z + c.w));
    }
    __syncthreads();
    float w[KTAP];
    {
        float tot = 0.f;
        #pragma unroll
        for (int q = 0; q < KTAP; ++q) tot += rsum[q];
        const float r = rsqrtf(tot);
        #pragma unroll
        for (int p = 0; p < KTAP; ++p) w[p] = rsum[KTAP - 1 - p] * r;
    }

    // --- XCD-chunked bijective swizzle (4096 blocks, 8 XCDs, 512 per chunk):
    //     consecutive new-ids within a chunk stay on one XCD -> ti-adjacent
    //     tiles of one image share that XCD's L2 (10-row halo reuse).
    const int bid = blockIdx.x;            // 0..4095
    const int nb  = (bid & 7) * 512 + (bid >> 3);
    const int img = nb >> 2;               // 0..1023
    const int ti  = nb & 3;                // 0..3 (32 out-rows each)

    const float* xim = x + (size_t)img * (H_IN * W_IN);
    float* oim = out + (size_t)img * (H_OUT * W_OUT);

    // ---- vertical pass: 136 tasks (rg 0..1 x cg 0..67), 16 out-rows x 4 cols
    if (tid < 136) {
        const int rg  = tid / FG;
        const int cg  = tid - rg * FG;
        const int col = -8 + 4 * cg;                     // global col of float4
        const bool colok = (unsigned)col < (unsigned)W_IN;  // pads auto-zero
        const int i0  = 16 * rg;                         // local out-row base
        const int gr0 = 64 * ti + 32 * rg - 5;           // first input row

        float4 acc[16];
        #pragma unroll
        for (int k = 0; k < 16; ++k) acc[k] = make_float4(0.f, 0.f, 0.f, 0.f);

        const float* rp = xim + (size_t)gr0 * W_IN + col;
        #pragma unroll
        for (int rr = 0; rr < 42; ++rr) {
            const int gr = gr0 + rr;
            float4 v = make_float4(0.f, 0.f, 0.f, 0.f);
            if (colok && (unsigned)gr < (unsigned)H_IN)
                v = *reinterpret_cast<const float4*>(rp);
            rp += W_IN;
            #pragma unroll
            for (int ri = 0; ri < 16; ++ri) {
                const int p = rr - 2 * ri;               // compile-time tap index
                if (p >= 0 && p < KTAP) {
                    acc[ri].x = fmaf(w[p], v.x, acc[ri].x);
                    acc[ri].y = fmaf(w[p], v.y, acc[ri].y);
                    acc[ri].z = fmaf(w[p], v.z, acc[ri].z);
                    acc[ri].w = fmaf(w[p], v.w, acc[ri].w);
                }
            }
        }
        #pragma unroll
        for (int ri = 0; ri < 16; ++ri)
            *reinterpret_cast<float4*>(&vs[(i0 + ri) * VSTR + 4 * cg]) = acc[ri];
    }
    __syncthreads();

    // ---- horizontal pass: 512 tasks (i 0..31 x g 0..15), 8 outputs each
    for (int t = tid; t < 512; t += NTHR) {
        const int i = t >> 4;
        const int g = t & 15;

        float f[32];
        #pragma unroll
        for (int m = 0; m < 8; ++m) {
            float4 v4 = *reinterpret_cast<const float4*>(&vs[i * VSTR + 16 * g + 4 * m]);
            f[4*m+0] = v4.x; f[4*m+1] = v4.y; f[4*m+2] = v4.z; f[4*m+3] = v4.w;
        }
        // output j = 8g+jj needs frame words 16g + 2jj+3 .. 16g + 2jj+14
        float o[8];
        #pragma unroll
        for (int jj = 0; jj < 8; ++jj) {
            float a = 0.f;
            #pragma unroll
            for (int q = 0; q < KTAP; ++q)
                a = fmaf(w[q], f[2*jj + 3 + q], a);
            o[jj] = a;
        }
        const int orow = 32 * ti + i;
        const int ocol = 8 * g;
        f32x4 o0 = { o[0], o[1], o[2], o[3] };
        f32x4 o1 = { o[4], o[5], o[6], o[7] };
        float* dst = oim + (size_t)orow * W_OUT + ocol;
        __builtin_nontemporal_store(o0, reinterpret_cast<f32x4*>(dst));
        __builtin_nontemporal_store(o1, reinterpret_cast<f32x4*>(dst + 4));
    }
}

extern "C" void kernel_launch(void* const* d_in, const int* in_sizes, int n_in,
                              void* d_out, int out_size, void* d_ws, size_t ws_size,
                              hipStream_t stream) {
    const float* x   = (const float*)d_in[0];
    const float* k2d = (const float*)d_in[1];
    float* out       = (float*)d_out;

    // 4 full-width tiles (32x128) per image, 1024 images = 4096 blocks
    dim3 grid(4096);
    dim3 block(NTHR);
    upfirdn2d_sym6<<<grid, block, 0, stream>>>(x, k2d, out);
}